// Round 13
// baseline (60122.620 us; speedup 1.0000x reference)
//
#include <hip/hip_runtime.h>
#include <math.h>

__global__ __launch_bounds__(256) void fill_kernel(float* p, int n, float v) {
  int i = blockIdx.x * 256 + threadIdx.x;
  if (i < n) p[i] = v;
}

// ---------------- strict-fp32 BN apply (reference op order, unfolded)
// coef[c*5]: mr, mi, Rrr, Rii, Rri
__device__ __forceinline__ void bn_apply_f32(float xr, float xi,
                                             const float* __restrict__ cf,
                                             float grr, float gri, float gii,
                                             float bbr, float bbi, float& yr,
                                             float& yi) {
  float cr = __fsub_rn(xr, cf[0]);
  float ci = __fsub_rn(xi, cf[1]);
  float xhr = __fadd_rn(__fmul_rn(cf[2], cr), __fmul_rn(cf[4], ci));
  float xhi = __fadd_rn(__fmul_rn(cf[4], cr), __fmul_rn(cf[3], ci));
  yr = fmaxf(__fadd_rn(__fadd_rn(__fmul_rn(grr, xhr), __fmul_rn(gri, xhi)), bbr), 0.f);
  yi = fmaxf(__fadd_rn(__fadd_rn(__fmul_rn(gri, xhr), __fmul_rn(gii, xhi)), bbi), 0.f);
}

// ---------------- conv1: fp32 FMA chain over (ky,kx) [cin=1]
__device__ __forceinline__ void conv1_out_f32(const float* __restrict__ x, int n,
                                              const float* __restrict__ wr,
                                              const float* __restrict__ wi,
                                              float addR, float addI, int co,
                                              int y, int xx, float& xr,
                                              float& xi) {
  const float* xn = x + (size_t)n * 4096;
  const float* wrc = wr + co * 121;
  const float* wic = wi + co * 121;
  float a = 0.f, b = 0.f;
  for (int ky = 0; ky < 11; ++ky) {
    int iy = y + ky - 5;
    if (iy < 0 || iy >= 64) continue;
    for (int kx = 0; kx < 11; ++kx) {
      int ix = xx + kx - 5;
      if (ix < 0 || ix >= 64) continue;
      float v = xn[iy * 64 + ix];
      a = fmaf(v, wrc[ky * 11 + kx], a);
      b = fmaf(v, wic[ky * 11 + kx], b);
    }
  }
  xr = __fadd_rn(a, addR);
  xi = __fadd_rn(b, addI);
}

// ---------------- complex conv: four fp32 FMA chains over (ky,kx,cin)
// [patch-major im2col / Eigen-NHWC contraction order: cin innermost]
// yr = fl(fl(A+br) - fl(B+bi)), yi = fl(fl(C+br) + fl(D+bi))
template <int H, int CIN, int K>
__device__ __forceinline__ void cconv_out_f32(
    const float* __restrict__ Xr, const float* __restrict__ Xi,
    const float* __restrict__ wr, const float* __restrict__ wi, float bR,
    float bI, int n, int co, int y, int xx, float& yr, float& yi) {
  constexpr int PAD = K / 2, KK = K * K, HH = H * H;
  const float* wrb = wr + (size_t)co * CIN * KK;
  const float* wib = wi + (size_t)co * CIN * KK;
  const float* xrb = Xr + (size_t)n * CIN * HH;
  const float* xib = Xi + (size_t)n * CIN * HH;
  float A = 0.f, B = 0.f, C = 0.f, D = 0.f;
  for (int ky = 0; ky < K; ++ky) {
    int iy = y + ky - PAD;
    if (iy < 0 || iy >= H) continue;
    for (int kx = 0; kx < K; ++kx) {
      int ix = xx + kx - PAD;
      if (ix < 0 || ix >= H) continue;
      int xoff = iy * H + ix, woff = ky * K + kx;
      for (int cin = 0; cin < CIN; ++cin) {
        float vr = xrb[cin * HH + xoff];
        float vi = xib[cin * HH + xoff];
        float wR = wrb[cin * KK + woff];
        float wI = wib[cin * KK + woff];
        A = fmaf(vr, wR, A);
        B = fmaf(vi, wI, B);
        C = fmaf(vi, wR, C);
        D = fmaf(vr, wI, D);
      }
    }
  }
  yr = __fsub_rn(__fadd_rn(A, bR), __fadd_rn(B, bI));
  yi = __fadd_rn(__fadd_rn(C, bR), __fadd_rn(D, bI));
}

// ================= numpy-pairwise fp32 statistics =================
// pairwise_sum: 128-elem base blocks with 8 interleaved chains combined
// ((r0+r1)+(r2+r3))+((r4+r5)+(r6+r7)); balanced adjacent-pair tree over
// blocks; planes accumulated sequentially over n (numpy multi-axis reduce).

template <int PASS>
__global__ __launch_bounds__(256) void conv1_np_stats(
    const float* __restrict__ x, const float* __restrict__ wr,
    const float* __restrict__ wi, const float* __restrict__ br,
    const float* __restrict__ bi, const float* __restrict__ coef,
    float* __restrict__ partial) {
  int b = blockIdx.x;
  int c = b & 15, n = b >> 4;
  int t = threadIdx.x;
  __shared__ float s0[256], s1[256], s2[256];
  {
    int leaf = t >> 3, j = t & 7;
    float a0 = 0.f, a1 = 0.f, a2 = 0.f;
    float addR = __fsub_rn(br[c], bi[c]);
    float addI = __fadd_rn(br[c], bi[c]);
    float mr = 0.f, mi = 0.f;
    if (PASS) { mr = coef[c * 5 + 0]; mi = coef[c * 5 + 1]; }
    for (int k = 0; k < 16; ++k) {
      int px = leaf * 128 + k * 8 + j;
      int y = px >> 6, xx = px & 63;
      float xr, xi;
      conv1_out_f32(x, n, wr, wi, addR, addI, c, y, xx, xr, xi);
      if (PASS == 0) {
        a0 = __fadd_rn(a0, xr);
        a1 = __fadd_rn(a1, xi);
      } else {
        float cr = __fsub_rn(xr, mr), ci = __fsub_rn(xi, mi);
        a0 = __fadd_rn(a0, __fmul_rn(cr, cr));
        a1 = __fadd_rn(a1, __fmul_rn(ci, ci));
        a2 = __fadd_rn(a2, __fmul_rn(cr, ci));
      }
    }
    s0[t] = a0; s1[t] = a1; s2[t] = a2;
  }
  __syncthreads();
  if (t == 0) {
    for (int L = 0; L < 32; ++L) {
      int o = L * 8;
      s0[L] = __fadd_rn(__fadd_rn(__fadd_rn(s0[o], s0[o + 1]), __fadd_rn(s0[o + 2], s0[o + 3])),
                        __fadd_rn(__fadd_rn(s0[o + 4], s0[o + 5]), __fadd_rn(s0[o + 6], s0[o + 7])));
      s1[L] = __fadd_rn(__fadd_rn(__fadd_rn(s1[o], s1[o + 1]), __fadd_rn(s1[o + 2], s1[o + 3])),
                        __fadd_rn(__fadd_rn(s1[o + 4], s1[o + 5]), __fadd_rn(s1[o + 6], s1[o + 7])));
      s2[L] = __fadd_rn(__fadd_rn(__fadd_rn(s2[o], s2[o + 1]), __fadd_rn(s2[o + 2], s2[o + 3])),
                        __fadd_rn(__fadd_rn(s2[o + 4], s2[o + 5]), __fadd_rn(s2[o + 6], s2[o + 7])));
    }
    for (int wdt = 32; wdt > 1; wdt >>= 1)
      for (int i = 0; i < (wdt >> 1); ++i) {
        s0[i] = __fadd_rn(s0[2 * i], s0[2 * i + 1]);
        s1[i] = __fadd_rn(s1[2 * i], s1[2 * i + 1]);
        s2[i] = __fadd_rn(s2[2 * i], s2[2 * i + 1]);
      }
    constexpr int S = PASS ? 3 : 2;
    size_t base = ((size_t)(n * 16 + c)) * S;
    partial[base + 0] = s0[0];
    partial[base + 1] = s1[0];
    if (PASS) partial[base + 2] = s2[0];
  }
}

template <int H, int CIN, int COUT, int K, int PASS>
__global__ __launch_bounds__(64) void cconv_np_stats(
    const float* __restrict__ Xr, const float* __restrict__ Xi,
    const float* __restrict__ wr, const float* __restrict__ wi,
    const float* __restrict__ br, const float* __restrict__ bi,
    const float* __restrict__ coef, float* __restrict__ partial) {
  constexpr int HH = H * H;
  constexpr int CHAINS = (HH >= 128) ? HH / 16 : 8;
  constexpr int CLEN = (HH >= 128) ? 16 : 8;
  constexpr int LEAVES = (HH >= 128) ? HH / 128 : 1;
  int b = blockIdx.x;
  int c = b % COUT, n = b / COUT;
  int t = threadIdx.x;
  __shared__ float s0[CHAINS], s1[CHAINS], s2[CHAINS];
  if (t < CHAINS) {
    int leaf = t >> 3, j = t & 7;
    float a0 = 0.f, a1 = 0.f, a2 = 0.f;
    float cbR = br[c], cbI = bi[c];
    float mr = 0.f, mi = 0.f;
    if (PASS) { mr = coef[c * 5 + 0]; mi = coef[c * 5 + 1]; }
    for (int k = 0; k < CLEN; ++k) {
      int px = leaf * 128 + k * 8 + j;
      int y = px / H, xx = px % H;
      float yr, yi;
      cconv_out_f32<H, CIN, K>(Xr, Xi, wr, wi, cbR, cbI, n, c, y, xx, yr, yi);
      if (PASS == 0) {
        a0 = __fadd_rn(a0, yr);
        a1 = __fadd_rn(a1, yi);
      } else {
        float cr = __fsub_rn(yr, mr), ci = __fsub_rn(yi, mi);
        a0 = __fadd_rn(a0, __fmul_rn(cr, cr));
        a1 = __fadd_rn(a1, __fmul_rn(ci, ci));
        a2 = __fadd_rn(a2, __fmul_rn(cr, ci));
      }
    }
    s0[t] = a0; s1[t] = a1; s2[t] = a2;
  }
  __syncthreads();
  if (t == 0) {
    for (int L = 0; L < LEAVES; ++L) {
      int o = L * 8;
      s0[L] = __fadd_rn(__fadd_rn(__fadd_rn(s0[o], s0[o + 1]), __fadd_rn(s0[o + 2], s0[o + 3])),
                        __fadd_rn(__fadd_rn(s0[o + 4], s0[o + 5]), __fadd_rn(s0[o + 6], s0[o + 7])));
      s1[L] = __fadd_rn(__fadd_rn(__fadd_rn(s1[o], s1[o + 1]), __fadd_rn(s1[o + 2], s1[o + 3])),
                        __fadd_rn(__fadd_rn(s1[o + 4], s1[o + 5]), __fadd_rn(s1[o + 6], s1[o + 7])));
      s2[L] = __fadd_rn(__fadd_rn(__fadd_rn(s2[o], s2[o + 1]), __fadd_rn(s2[o + 2], s2[o + 3])),
                        __fadd_rn(__fadd_rn(s2[o + 4], s2[o + 5]), __fadd_rn(s2[o + 6], s2[o + 7])));
    }
    for (int wdt = LEAVES; wdt > 1; wdt >>= 1)
      for (int i = 0; i < (wdt >> 1); ++i) {
        s0[i] = __fadd_rn(s0[2 * i], s0[2 * i + 1]);
        s1[i] = __fadd_rn(s1[2 * i], s1[2 * i + 1]);
        s2[i] = __fadd_rn(s2[2 * i], s2[2 * i + 1]);
      }
    constexpr int S = PASS ? 3 : 2;
    size_t base = ((size_t)(n * COUT + c)) * S;
    partial[base + 0] = s0[0];
    partial[base + 1] = s1[0];
    if (PASS) partial[base + 2] = s2[0];
  }
}

// ---- combine over n (sequential fp32, numpy outer-axis order), then coef
template <int C, int TPB>
__global__ __launch_bounds__(TPB) void np_mean_combine(
    const float* __restrict__ partial, float* __restrict__ coef, float Mf) {
  int t = threadIdx.x;
  if (t >= C * 2) return;
  int c = t >> 1, s = t & 1;
  float acc = 0.f;
  for (int n = 0; n < 512; ++n)
    acc = __fadd_rn(acc, partial[((size_t)n * C + c) * 2 + s]);
  coef[c * 5 + s] = __fdiv_rn(acc, Mf);
}

template <int C, int TPB>
__global__ __launch_bounds__(TPB) void np_cov_combine(
    const float* __restrict__ partial, float* __restrict__ coef, float Mf) {
  __shared__ float sums[C * 3];
  int t = threadIdx.x;
  if (t < C * 3) {
    int c = t / 3, s = t % 3;
    float acc = 0.f;
    for (int n = 0; n < 512; ++n)
      acc = __fadd_rn(acc, partial[((size_t)n * C + c) * 3 + s]);
    sums[c * 3 + s] = acc;
  }
  __syncthreads();
  if (t < C) {
    float Crr = __fadd_rn(__fdiv_rn(sums[t * 3 + 0], Mf), 1e-5f);
    float Cii = __fadd_rn(__fdiv_rn(sums[t * 3 + 1], Mf), 1e-5f);
    float Cri = __fdiv_rn(sums[t * 3 + 2], Mf);
    float s_ = __fsqrt_rn(__fsub_rn(__fmul_rn(Crr, Cii), __fmul_rn(Cri, Cri)));
    float t_ = __fsqrt_rn(__fadd_rn(__fadd_rn(Crr, Cii), __fmul_rn(2.f, s_)));
    float inv = __fdiv_rn(1.f, __fmul_rn(s_, t_));
    coef[t * 5 + 2] = __fmul_rn(__fadd_rn(Cii, s_), inv);   // Rrr
    coef[t * 5 + 3] = __fmul_rn(__fadd_rn(Crr, s_), inv);   // Rii
    coef[t * 5 + 4] = __fmul_rn(-Cri, inv);                 // Rri
  }
}

// ---------------- pool passes (strict fp32, recompute conv)
__global__ __launch_bounds__(256) void conv1_pool_kernel(
    const float* __restrict__ x, const float* __restrict__ wr,
    const float* __restrict__ wi, const float* __restrict__ br,
    const float* __restrict__ bi, const float* __restrict__ coef,
    const float* __restrict__ grr, const float* __restrict__ gri,
    const float* __restrict__ gii, const float* __restrict__ bbr,
    const float* __restrict__ bbi, float* __restrict__ Pr,
    float* __restrict__ Pi) {
  int g = blockIdx.x * 256 + threadIdx.x;
  int plane = g >> 10, q = g & 1023;
  int c = plane & 15, n = plane >> 4;
  int oy = q >> 5, ox = q & 31;
  float addR = __fsub_rn(br[c], bi[c]);
  float addI = __fadd_rn(br[c], bi[c]);
  const float* cf = coef + c * 5;
  float gR = grr[c], gI = gri[c], gG = gii[c], bR = bbr[c], bI = bbi[c];
  float bestr = 0.f, besti = 0.f, bestm = -1.f;
#pragma unroll
  for (int p = 0; p < 4; ++p) {  // (0,0),(0,1),(1,0),(1,1): first-occurrence argmax
    int y = 2 * oy + (p >> 1), xx = 2 * ox + (p & 1);
    float xr, xi;
    conv1_out_f32(x, n, wr, wi, addR, addI, c, y, xx, xr, xi);
    float yr, yi;
    bn_apply_f32(xr, xi, cf, gR, gI, gG, bR, bI, yr, yi);
    float m = __fadd_rn(__fmul_rn(yr, yr), __fmul_rn(yi, yi));
    if (m > bestm) { bestm = m; bestr = yr; besti = yi; }
  }
  size_t o = ((size_t)(n * 16 + c) * 32 + oy) * 32 + ox;
  Pr[o] = bestr;
  Pi[o] = besti;
}

template <int H, int CIN, int COUT, int K>
__global__ __launch_bounds__(256) void cconv_pool_kernel(
    const float* __restrict__ Xr, const float* __restrict__ Xi,
    const float* __restrict__ wr, const float* __restrict__ wi,
    const float* __restrict__ br, const float* __restrict__ bi,
    const float* __restrict__ coef, const float* __restrict__ grr,
    const float* __restrict__ gri, const float* __restrict__ gii,
    const float* __restrict__ bbr, const float* __restrict__ bbi,
    float* __restrict__ Pr, float* __restrict__ Pi) {
  constexpr int OH = H / 2, OHH = OH * OH;
  int g = blockIdx.x * 256 + threadIdx.x;
  int plane = g / OHH, q = g % OHH;
  int c = plane % COUT, n = plane / COUT;
  int oy = q / OH, ox = q % OH;
  float cbR = br[c], cbI = bi[c];
  const float* cf = coef + c * 5;
  float gR = grr[c], gI = gri[c], gG = gii[c], bR = bbr[c], bI = bbi[c];
  float bestr = 0.f, besti = 0.f, bestm = -1.f;
#pragma unroll
  for (int p = 0; p < 4; ++p) {
    int y = 2 * oy + (p >> 1), xx = 2 * ox + (p & 1);
    float xr, xi;
    cconv_out_f32<H, CIN, K>(Xr, Xi, wr, wi, cbR, cbI, n, c, y, xx, xr, xi);
    float yr, yi;
    bn_apply_f32(xr, xi, cf, gR, gI, gG, bR, bI, yr, yi);
    float m = __fadd_rn(__fmul_rn(yr, yr), __fmul_rn(yi, yi));
    if (m > bestm) { bestm = m; bestr = yr; besti = yi; }
  }
  size_t o = ((size_t)(n * COUT + c) * OH + oy) * OH + ox;
  Pr[o] = bestr;
  Pi[o] = besti;
}

// ---------------- fused FC head (fp64 accumulate; linear)
__global__ __launch_bounds__(256) void fc_head_kernel(
    const float* __restrict__ Fr, const float* __restrict__ Fi,
    const float* __restrict__ wr, const float* __restrict__ wi,
    const float* __restrict__ br, const float* __restrict__ bi,
    const float* __restrict__ w2, const float* __restrict__ b2,
    float* __restrict__ logits, float* __restrict__ er_out,
    float* __restrict__ ei_out) {
  int n = blockIdx.x, t = threadIdx.x;
  __shared__ float sFr[1024], sFi[1024];
  __shared__ double sMag[256];
  for (int idx = t; idx < 1024; idx += 256) {
    sFr[idx] = Fr[(size_t)n * 1024 + idx];
    sFi[idx] = Fi[(size_t)n * 1024 + idx];
  }
  __syncthreads();
  {
    const float* wro = wr + t * 1024;
    const float* wio = wi + t * 1024;
    double er = 0.0, ei = 0.0;
    for (int k = 0; k < 1024; ++k) {
      double fx = (double)sFr[k], fy = (double)sFi[k];
      double a = (double)wro[k], bb = (double)wio[k];
      er += fx * a - fy * bb;
      ei += fy * a + fx * bb;
    }
    double bR = (double)br[t], bI = (double)bi[t];
    er = fmax(er + (bR - bI), 0.0);
    ei = fmax(ei + (bR + bI), 0.0);
    er_out[(size_t)n * 256 + t] = (float)er;
    ei_out[(size_t)n * 256 + t] = (float)ei;
    sMag[t] = sqrt(er * er + ei * ei + 1e-12);
  }
  __syncthreads();
#pragma unroll
  for (int j = 0; j < 4; ++j) {
    int o = j * 256 + t;
    if (o < 1000) {
      const float* wo = w2 + o * 256;
      double acc = 0.0;
      for (int k = 0; k < 256; ++k) acc += sMag[k] * (double)wo[k];
      logits[(size_t)n * 1000 + o] = (float)(acc + (double)b2[o]);
    }
  }
}

// ---------------- launch
extern "C" void kernel_launch(void* const* d_in, const int* in_sizes, int n_in,
                              void* d_out, int out_size, void* d_ws,
                              size_t ws_size, hipStream_t stream) {
  (void)in_sizes; (void)n_in;
  const float* x = (const float*)d_in[0];
  const float* c1_wr = (const float*)d_in[1];
  const float* c1_wi = (const float*)d_in[2];
  const float* c1_br = (const float*)d_in[3];
  const float* c1_bi = (const float*)d_in[4];
  const float* c2_wr = (const float*)d_in[5];
  const float* c2_wi = (const float*)d_in[6];
  const float* c2_br = (const float*)d_in[7];
  const float* c2_bi = (const float*)d_in[8];
  const float* c3_wr = (const float*)d_in[9];
  const float* c3_wi = (const float*)d_in[10];
  const float* c3_br = (const float*)d_in[11];
  const float* c3_bi = (const float*)d_in[12];
  const float* c4_wr = (const float*)d_in[13];
  const float* c4_wi = (const float*)d_in[14];
  const float* c4_br = (const float*)d_in[15];
  const float* c4_bi = (const float*)d_in[16];
  const float* b1_grr = (const float*)d_in[17];
  const float* b1_gri = (const float*)d_in[18];
  const float* b1_gii = (const float*)d_in[19];
  const float* b1_br = (const float*)d_in[20];
  const float* b1_bi = (const float*)d_in[21];
  const float* b2_grr = (const float*)d_in[22];
  const float* b2_gri = (const float*)d_in[23];
  const float* b2_gii = (const float*)d_in[24];
  const float* b2_br = (const float*)d_in[25];
  const float* b2_bi = (const float*)d_in[26];
  const float* b3_grr = (const float*)d_in[27];
  const float* b3_gri = (const float*)d_in[28];
  const float* b3_gii = (const float*)d_in[29];
  const float* b3_br = (const float*)d_in[30];
  const float* b3_bi = (const float*)d_in[31];
  const float* b4_grr = (const float*)d_in[32];
  const float* b4_gri = (const float*)d_in[33];
  const float* b4_gii = (const float*)d_in[34];
  const float* b4_br = (const float*)d_in[35];
  const float* b4_bi = (const float*)d_in[36];
  const float* fc1_wr = (const float*)d_in[37];
  const float* fc1_wi = (const float*)d_in[38];
  const float* fc1_br = (const float*)d_in[39];
  const float* fc1_bi = (const float*)d_in[40];
  const float* fc2_w = (const float*)d_in[41];
  const float* fc2_b = (const float*)d_in[42];

  float* outL = (float*)d_out;
  float* er = outL + 512 * 1000;
  float* ei = er + 512 * 256;

  // Workspace (same proven layout as R11):
  //   P1r @0 (33.5M)  P1i @33,554,432
  //   P2r @67,108,864 (16.8M)  P2i @83,886,080 -> end 100,663,296
  //   P3r @0 (8.4M; P1 dead)  P3i @8,388,608
  //   P4r @16,777,216 (2.1M)  P4i @18,874,368
  //   partial @100,663,296 (max 393,216)  coef @101,056,512 (1,280)
  const size_t NEED = 101057792;  // proven available (R11 ran)
  if (ws_size < NEED) {
    fill_kernel<<<(out_size + 255) / 256, 256, 0, stream>>>(
        (float*)d_out, out_size, (float)(ws_size >> 20));
    return;
  }
  char* w = (char*)d_ws;
  float* P1r = (float*)(w + 0);
  float* P1i = (float*)(w + 33554432);
  float* P2r = (float*)(w + 67108864);
  float* P2i = (float*)(w + 83886080);
  float* P3r = (float*)(w + 0);
  float* P3i = (float*)(w + 8388608);
  float* P4r = (float*)(w + 16777216);
  float* P4i = (float*)(w + 18874368);
  float* partial = (float*)(w + 100663296);
  float* coef = (float*)(w + 101056512);

  // ---- layer 1 (C=16, HH=4096, M=2097152)
  conv1_np_stats<0><<<8192, 256, 0, stream>>>(x, c1_wr, c1_wi, c1_br, c1_bi,
                                              coef, partial);
  np_mean_combine<16, 64><<<1, 64, 0, stream>>>(partial, coef, 2097152.f);
  conv1_np_stats<1><<<8192, 256, 0, stream>>>(x, c1_wr, c1_wi, c1_br, c1_bi,
                                              coef, partial);
  np_cov_combine<16, 64><<<1, 64, 0, stream>>>(partial, coef, 2097152.f);
  conv1_pool_kernel<<<32768, 256, 0, stream>>>(x, c1_wr, c1_wi, c1_br, c1_bi,
                                               coef, b1_grr, b1_gri, b1_gii,
                                               b1_br, b1_bi, P1r, P1i);

  // ---- layer 2 (C=32, HH=1024, M=524288)
  cconv_np_stats<32, 16, 32, 5, 0><<<16384, 64, 0, stream>>>(
      P1r, P1i, c2_wr, c2_wi, c2_br, c2_bi, coef, partial);
  np_mean_combine<32, 64><<<1, 64, 0, stream>>>(partial, coef, 524288.f);
  cconv_np_stats<32, 16, 32, 5, 1><<<16384, 64, 0, stream>>>(
      P1r, P1i, c2_wr, c2_wi, c2_br, c2_bi, coef, partial);
  np_cov_combine<32, 128><<<1, 128, 0, stream>>>(partial, coef, 524288.f);
  cconv_pool_kernel<32, 16, 32, 5><<<16384, 256, 0, stream>>>(
      P1r, P1i, c2_wr, c2_wi, c2_br, c2_bi, coef, b2_grr, b2_gri, b2_gii,
      b2_br, b2_bi, P2r, P2i);

  // ---- layer 3 (C=64, HH=256, M=131072) — P3 overlays dead P1; reads P2
  cconv_np_stats<16, 32, 64, 3, 0><<<32768, 64, 0, stream>>>(
      P2r, P2i, c3_wr, c3_wi, c3_br, c3_bi, coef, partial);
  np_mean_combine<64, 128><<<1, 128, 0, stream>>>(partial, coef, 131072.f);
  cconv_np_stats<16, 32, 64, 3, 1><<<32768, 64, 0, stream>>>(
      P2r, P2i, c3_wr, c3_wi, c3_br, c3_bi, coef, partial);
  np_cov_combine<64, 192><<<1, 192, 0, stream>>>(partial, coef, 131072.f);
  cconv_pool_kernel<16, 32, 64, 3><<<8192, 256, 0, stream>>>(
      P2r, P2i, c3_wr, c3_wi, c3_br, c3_bi, coef, b3_grr, b3_gri, b3_gii,
      b3_br, b3_bi, P3r, P3i);

  // ---- layer 4 (C=64, HH=64, M=32768) — reads P3, writes P4 (disjoint)
  cconv_np_stats<8, 64, 64, 3, 0><<<32768, 64, 0, stream>>>(
      P3r, P3i, c4_wr, c4_wi, c4_br, c4_bi, coef, partial);
  np_mean_combine<64, 128><<<1, 128, 0, stream>>>(partial, coef, 32768.f);
  cconv_np_stats<8, 64, 64, 3, 1><<<32768, 64, 0, stream>>>(
      P3r, P3i, c4_wr, c4_wi, c4_br, c4_bi, coef, partial);
  np_cov_combine<64, 192><<<1, 192, 0, stream>>>(partial, coef, 32768.f);
  cconv_pool_kernel<8, 64, 64, 3><<<2048, 256, 0, stream>>>(
      P3r, P3i, c4_wr, c4_wi, c4_br, c4_bi, coef, b4_grr, b4_gri, b4_gii,
      b4_br, b4_bi, P4r, P4i);

  // ---- FC head
  fc_head_kernel<<<512, 256, 0, stream>>>(P4r, P4i, fc1_wr, fc1_wi, fc1_br,
                                          fc1_bi, fc2_w, fc2_b, outL, er, ei);
}